// Round 9
// baseline (4513.359 us; speedup 1.0000x reference)
//
#include <hip/hip_runtime.h>
#include <hip/hip_bf16.h>

#define S 2048
#define NEGV -10000.0f
#define REPS 8
#define REPSTRIDE 2112   // ull units: 2dir*2slot*512 + 64 pad = 16.5KB

typedef unsigned long long ull;
typedef unsigned int uint4v __attribute__((ext_vector_type(4)));

__device__ __forceinline__ float fsig(float x) {
  return 1.0f / (1.0f + __expf(-x));
}
__device__ __forceinline__ float ftanh(float x) {
  float a = fabsf(x);
  float e = __expf(-2.0f * a);
  float r = (1.0f - e) / (1.0f + e);
  return copysignf(r, x);
}

// ---------------- init: seed h0 (stamp 1) in all replicas + clear flags ----------------
__global__ void init_k(const float* __restrict__ h0, ull* __restrict__ hbuf,
                       int* __restrict__ flags) {
  int b = blockIdx.x, u = threadIdx.x;
  if (b < 16) {                        // replica init: b = rep*2 + dir
    int rep = b >> 1, dir = b & 1;
    ull* base = hbuf + rep * REPSTRIDE + dir * 1024;
    ull pk = (1ULL << 32) | (ull)__float_as_uint(h0[dir * 512 + u]);
    __hip_atomic_store(&base[u], pk, __ATOMIC_RELAXED, __HIP_MEMORY_SCOPE_AGENT);
    __hip_atomic_store(&base[512 + u], 0ULL, __ATOMIC_RELAXED, __HIP_MEMORY_SCOPE_AGENT);
  } else {                             // flags clear: blocks 16,17
    int i = (b - 16) * 1024 + u;
    flags[i] = 0;
    flags[i + 512] = 0;
  }
}

// ---------------- FUSED: blocks 0..127 LSTM, 128..255 persistent GEMM ----------------
// One block per CU. GEMM: chain-head-priority tiles, agent write-through publish + flag.
// LSTM: R5 chain + (a) 8x-replicated stamp buffers (kills LLC hot-line bursts),
// (b) two staggered in-flight polls, vmcnt(1) alternating waits (halves discovery
// overshoot), register-tied waitcnt asm for ordering.
__global__ __launch_bounds__(256) void fused_k(
    const int* __restrict__ sent, const float* __restrict__ emb,
    const float* __restrict__ Wih_f, const float* __restrict__ Wih_b,
    const float* __restrict__ bih_f, const float* __restrict__ bhh_f,
    const float* __restrict__ bih_b, const float* __restrict__ bhh_b,
    const float* __restrict__ Whh_f, const float* __restrict__ Whh_b,
    const float* __restrict__ c0,
    float* __restrict__ xg,            // [S][4096]
    ull* __restrict__ hbuf,            // [REPS][2 dir][2 slot][512] (+pad)
    float* __restrict__ hs_cat,        // [S][1024]
    int* __restrict__ flags)           // [32 by][64 bx]
{
  __shared__ __align__(16) float smem[4544];
  const int t = threadIdx.x;

  if (blockIdx.x >= 128) {
    // ================= persistent GEMM worker =================
    float* Asm = smem;                 // [64][36]
    float* Bsm = smem + 2304;          // [32][68]
    int*   sidx = (int*)(smem + 4480); // [64]
    const int tm = t >> 4, tn = t & 15;
    const int lr = t >> 2, lkq = t & 3;

    for (int i = 0; i < 16; ++i) {
      const int T = (blockIdx.x - 128) + 128 * i;   // priority rank
      const int byo = T >> 6, bxo = T & 63;
      const int by = (byo & 1) ? (31 - (byo >> 1)) : (byo >> 1);
      const int bx = (bxo & 1) ? (32 + (bxo >> 1)) : (bxo >> 1);
      const int n0 = bx * 64, m0 = by * 64;

      const float* W = (n0 < 2048) ? (Wih_f + (size_t)n0 * 1024)
                                   : (Wih_b + (size_t)(n0 - 2048) * 1024);
      __syncthreads();
      if (t < 64) sidx[t] = sent[m0 + t];
      __syncthreads();

      float acc[4][4] = {};
      for (int k0 = 0; k0 < 1024; k0 += 32) {
        const float* ap = emb + (size_t)sidx[lr] * 1024 + k0 + lkq * 8;
        float4 a0 = *(const float4*)ap;
        float4 a1 = *(const float4*)(ap + 4);
        const float* bp = W + (size_t)lr * 1024 + k0 + lkq * 8;
        float4 b0 = *(const float4*)bp;
        float4 b1 = *(const float4*)(bp + 4);
        __syncthreads();
        *(float4*)&Asm[lr * 36 + lkq * 8]     = a0;
        *(float4*)&Asm[lr * 36 + lkq * 8 + 4] = a1;
        {
          const float* bb0 = (const float*)&b0;
          const float* bb1 = (const float*)&b1;
          #pragma unroll
          for (int j = 0; j < 4; ++j) Bsm[(lkq * 8 + j) * 68 + lr] = bb0[j];
          #pragma unroll
          for (int j = 0; j < 4; ++j) Bsm[(lkq * 8 + 4 + j) * 68 + lr] = bb1[j];
        }
        __syncthreads();
        #pragma unroll
        for (int kk = 0; kk < 32; ++kk) {
          float a0_ = Asm[(tm * 4 + 0) * 36 + kk];
          float a1_ = Asm[(tm * 4 + 1) * 36 + kk];
          float a2_ = Asm[(tm * 4 + 2) * 36 + kk];
          float a3_ = Asm[(tm * 4 + 3) * 36 + kk];
          float4 bv = *(const float4*)&Bsm[kk * 68 + tn * 4];
          acc[0][0] = fmaf(a0_, bv.x, acc[0][0]); acc[0][1] = fmaf(a0_, bv.y, acc[0][1]);
          acc[0][2] = fmaf(a0_, bv.z, acc[0][2]); acc[0][3] = fmaf(a0_, bv.w, acc[0][3]);
          acc[1][0] = fmaf(a1_, bv.x, acc[1][0]); acc[1][1] = fmaf(a1_, bv.y, acc[1][1]);
          acc[1][2] = fmaf(a1_, bv.z, acc[1][2]); acc[1][3] = fmaf(a1_, bv.w, acc[1][3]);
          acc[2][0] = fmaf(a2_, bv.x, acc[2][0]); acc[2][1] = fmaf(a2_, bv.y, acc[2][1]);
          acc[2][2] = fmaf(a2_, bv.z, acc[2][2]); acc[2][3] = fmaf(a2_, bv.w, acc[2][3]);
          acc[3][0] = fmaf(a3_, bv.x, acc[3][0]); acc[3][1] = fmaf(a3_, bv.y, acc[3][1]);
          acc[3][2] = fmaf(a3_, bv.z, acc[3][2]); acc[3][3] = fmaf(a3_, bv.w, acc[3][3]);
        }
      }

      const float* bi = (n0 < 2048) ? bih_f : bih_b;
      const float* bh = (n0 < 2048) ? bhh_f : bhh_b;
      const int nb = (n0 < 2048) ? n0 : (n0 - 2048);
      #pragma unroll
      for (int ii = 0; ii < 4; ++ii) {
        int m = m0 + tm * 4 + ii;
        #pragma unroll
        for (int j = 0; j < 4; ++j) {
          int nn = tn * 4 + j;
          float bias = bi[nb + nn] + bh[nb + nn];
          __hip_atomic_store(&xg[(size_t)m * 4096 + n0 + nn], acc[ii][j] + bias,
                             __ATOMIC_RELAXED, __HIP_MEMORY_SCOPE_AGENT);
        }
      }
      asm volatile("s_waitcnt vmcnt(0)" ::: "memory");
      __syncthreads();
      if (t == 0)
        __hip_atomic_store(&flags[by * 64 + bx], 1, __ATOMIC_RELAXED, __HIP_MEMORY_SCOPE_AGENT);
    }
    return;
  }

  // ================= LSTM role =================
  const int w = blockIdx.x;
  const int dir = w & 1;
  const int wid = w >> 1;              // 0..63
  const int rr = t >> 3;               // row-in-wg 0..31
  const int seg = t & 7;               // 0..7
  const int g  = rr & 3;               // gate 0..3 (i,f,g,o)
  const int ul = rr >> 2;              // local unit 0..7
  const int unit = wid * 8 + ul;       // 0..511
  const int grow = g * 512 + unit;     // global Whh row
  const int bxf  = dir * 32 + g * 8 + (wid >> 3);   // flag column for this row's xg

  float (*h_lds)[544] = (float(*)[544])smem;        // [2][544]

  const float* Whh = dir ? Whh_b : Whh_f;
  float wreg[64];
  {
    const float* src = Whh + (size_t)grow * 512 + seg * 64;
    #pragma unroll
    for (int j = 0; j < 16; ++j) {
      float4 v = *(const float4*)(src + j * 4);
      wreg[4 * j + 0] = v.x; wreg[4 * j + 1] = v.y;
      wreg[4 * j + 2] = v.z; wreg[4 * j + 3] = v.w;
    }
  }

  ull* hbr = hbuf + (wid & 7) * REPSTRIDE + dir * 1024;   // my poll replica
  ull* hbp = hbuf + dir * 1024;                           // publish base (replica 0)

  float c_reg = c0[dir * 512 + unit];  // meaningful on g==0 lanes

  const int u0 = t * 2;
  const int wchunk = u0 >> 6, wpos = u0 & 63;

  // initial xg: gate on the chain-head tile flags, then coherent loads
  float xg_a = 0.0f, xg_b = 0.0f;
  if (seg == 0) {
    int by0 = dir ? 31 : 0;
    while (__hip_atomic_load(&flags[by0 * 64 + bxf], __ATOMIC_RELAXED,
                             __HIP_MEMORY_SCOPE_AGENT) != 1)
      __builtin_amdgcn_s_sleep(8);
    int r0 = dir ? (S - 1) : 0;
    int r1 = dir ? (S - 2) : 1;
    xg_a = __hip_atomic_load(&xg[(size_t)r0 * 4096 + dir * 2048 + grow],
                             __ATOMIC_RELAXED, __HIP_MEMORY_SCOPE_AGENT);
    xg_b = __hip_atomic_load(&xg[(size_t)r1 * 4096 + dir * 2048 + grow],
                             __ATOMIC_RELAXED, __HIP_MEMORY_SCOPE_AGENT);
  }

  #define LSTM_STEP(K, XG_REG)                                                  \
  {                                                                             \
    const int k = (K);                                                          \
    float xgv = XG_REG;                                                         \
    if (seg == 0 && k + 2 < S) {       /* prefetch row k+2 into same reg */     \
      int rowk = dir ? (S - 3 - k) : (k + 2);                                   \
      if ((rowk & 63) == (dir ? 63 : 0)) {   /* entering new 64-row block */    \
        int byn = rowk >> 6;                                                    \
        while (__hip_atomic_load(&flags[byn * 64 + bxf], __ATOMIC_RELAXED,      \
                                 __HIP_MEMORY_SCOPE_AGENT) != 1)                \
          __builtin_amdgcn_s_sleep(8);                                          \
      }                                                                         \
      XG_REG = __hip_atomic_load(&xg[(size_t)rowk * 4096 + dir * 2048 + grow],  \
                                 __ATOMIC_RELAXED, __HIP_MEMORY_SCOPE_AGENT);   \
    }                                                                           \
    /* poll h_k: stamp k+1 in slot k&1; two staggered in-flight 16B polls */    \
    {                                                                           \
      ull* src = hbr + (k & 1) * 512 + u0;                                      \
      const unsigned want = (unsigned)(k + 1);                                  \
      uint4v va, vb;                                                            \
      asm volatile("s_waitcnt vmcnt(0)" ::: "memory");   /* drain stores/xg */  \
      asm volatile("global_load_dwordx4 %0, %1, off sc0 sc1"                    \
                   : "=v"(va) : "v"(src) : "memory");                           \
      __builtin_amdgcn_s_sleep(4);                       /* ~L/2 stagger */     \
      asm volatile("global_load_dwordx4 %0, %1, off sc0 sc1"                    \
                   : "=v"(vb) : "v"(src) : "memory");                           \
      for (;;) {                                                                \
        asm volatile("s_waitcnt vmcnt(1)" : "+v"(va) :: "memory");              \
        if (va.y == want && va.w == want) {                                     \
          asm volatile("s_waitcnt vmcnt(0)" : "+v"(va) :: "memory");            \
          vb = va; break;                                                       \
        }                                                                       \
        asm volatile("global_load_dwordx4 %0, %1, off sc0 sc1"                  \
                     : "=v"(va) : "v"(src) : "memory");                         \
        asm volatile("s_waitcnt vmcnt(1)" : "+v"(vb) :: "memory");              \
        if (vb.y == want && vb.w == want) {                                     \
          asm volatile("s_waitcnt vmcnt(0)" : "+v"(vb) :: "memory");            \
          break;                                                                \
        }                                                                       \
        asm volatile("global_load_dwordx4 %0, %1, off sc0 sc1"                  \
                     : "=v"(vb) : "v"(src) : "memory");                         \
      }                                                                         \
      float* dst = &h_lds[k & 1][wchunk * 68 + wpos];                           \
      dst[0] = __uint_as_float(vb.x);                                           \
      dst[1] = __uint_as_float(vb.z);                                           \
    }                                                                           \
    __syncthreads();                                                            \
    /* 64-wide partial dot of row `grow` */                                     \
    const float* hl = &h_lds[k & 1][0];                                         \
    float p0 = 0.f, p1 = 0.f, p2 = 0.f, p3 = 0.f;                               \
    const float4* h4 = (const float4*)(hl + seg * 68);                          \
    _Pragma("unroll")                                                           \
    for (int j = 0; j < 16; ++j) {                                              \
      float4 hv = h4[j];                                                        \
      p0 = fmaf(wreg[4 * j + 0], hv.x, p0);                                     \
      p1 = fmaf(wreg[4 * j + 1], hv.y, p1);                                     \
      p2 = fmaf(wreg[4 * j + 2], hv.z, p2);                                     \
      p3 = fmaf(wreg[4 * j + 3], hv.w, p3);                                     \
    }                                                                           \
    float p = (p0 + p1) + (p2 + p3) + xgv;                                      \
    p += __shfl_xor(p, 1);                                                      \
    p += __shfl_xor(p, 2);                                                      \
    p += __shfl_xor(p, 4);                                                      \
    float gb_ = __shfl_xor(p, 8);      /* gate g^1 */                           \
    float gc_ = __shfl_xor(p, 16);     /* gate g^2 */                           \
    float gd_ = __shfl_xor(gb_, 16);   /* gate g^3 */                           \
    if (g == 0) {                                                               \
      float iv = fsig(p), fv = fsig(gb_), ov = fsig(gd_);                       \
      float gv = ftanh(gc_);                                                    \
      c_reg = fv * c_reg + iv * gv;                                             \
      float hv = ov * ftanh(c_reg);                                             \
      if (seg == 0) {                                                           \
        ull pk = ((ull)(unsigned)(k + 2) << 32) | (ull)__float_as_uint(hv);     \
        ull* pb = hbp + ((k + 1) & 1) * 512 + unit;                             \
        _Pragma("unroll")                                                       \
        for (int rp = 0; rp < REPS; ++rp)                                       \
          __hip_atomic_store(pb + rp * REPSTRIDE, pk,                           \
                             __ATOMIC_RELAXED, __HIP_MEMORY_SCOPE_AGENT);       \
        int orig = dir ? (S - 1 - k) : k;                                       \
        hs_cat[(size_t)orig * 1024 + dir * 512 + unit] = hv;                    \
      }                                                                         \
    }                                                                           \
  }

  for (int kk = 0; kk < S; kk += 2) {
    LSTM_STEP(kk, xg_a);
    LSTM_STEP(kk + 1, xg_b);
  }
  #undef LSTM_STEP
}

// ---------------- feats[t][j] = hs_cat[t] . Wout[j] + bout[j] ----------------
__global__ __launch_bounds__(64) void feats_k(
    const float* __restrict__ hs_cat, const float* __restrict__ Wout,
    const float* __restrict__ bout, float* __restrict__ feats)
{
  int tpos = blockIdx.x;
  int l = threadIdx.x;
  int j = l & 15, q = l >> 4;
  const float* h = hs_cat + (size_t)tpos * 1024 + q * 256;
  const float* wv = Wout + (size_t)j * 1024 + q * 256;
  float s = 0.f;
  #pragma unroll 8
  for (int i = 0; i < 256; i += 4) {
    float4 hv = *(const float4*)(h + i);
    float4 ww = *(const float4*)(wv + i);
    s = fmaf(hv.x, ww.x, s); s = fmaf(hv.y, ww.y, s);
    s = fmaf(hv.z, ww.z, s); s = fmaf(hv.w, ww.w, s);
  }
  s += __shfl_xor(s, 16);
  s += __shfl_xor(s, 32);
  if (q == 0) feats[tpos * 16 + j] = s + bout[j];
}

// ---------------- Viterbi: single wave, LDS-chunked feats, 4-bit backpointers ----------------
__global__ __launch_bounds__(64, 1) void viterbi_k(
    const float* __restrict__ feats, const float* __restrict__ trans,
    float* __restrict__ out)
{
  __shared__ __align__(16) float fch[2][256 * 16];  // 2 x 16KB double-buffer
  __shared__ unsigned char bp4[S * 8];              // 16KB packed nibbles
  __shared__ float v_lds[2][16];                    // double-buffered by step parity

  const int l = threadIdx.x;
  const int next = l & 15, q = l >> 4;

  float tr0 = trans[next * 16 + q * 4 + 0];
  float tr1 = trans[next * 16 + q * 4 + 1];
  float tr2 = trans[next * 16 + q * 4 + 2];
  float tr3 = trans[next * 16 + q * 4 + 3];

  if (l < 16) v_lds[0][l] = (l == 0) ? 0.0f : NEGV;   // START = 0

  const float4* f4 = (const float4*)feats;
  float4 buf[16];
  #pragma unroll
  for (int i = 0; i < 16; ++i) buf[i] = f4[i * 64 + l];
  #pragma unroll
  for (int i = 0; i < 16; ++i) ((float4*)fch[0])[i * 64 + l] = buf[i];
  __syncthreads();

  for (int c = 0; c < 8; ++c) {
    if (c < 7) {
      #pragma unroll
      for (int i = 0; i < 16; ++i) buf[i] = f4[(c + 1) * 1024 + i * 64 + l];
    }
    const float* fc = fch[c & 1];
    for (int tt = 0; tt < 256; ++tt) {
      int t = c * 256 + tt;
      int pb = t & 1;
      const float* vin = v_lds[pb];
      float m = vin[q * 4 + 0] + tr0; int mi = q * 4;
      float s1 = vin[q * 4 + 1] + tr1; if (s1 > m) { m = s1; mi = q * 4 + 1; }
      float s2 = vin[q * 4 + 2] + tr2; if (s2 > m) { m = s2; mi = q * 4 + 2; }
      float s3 = vin[q * 4 + 3] + tr3; if (s3 > m) { m = s3; mi = q * 4 + 3; }
      #pragma unroll
      for (int mask = 16; mask <= 32; mask <<= 1) {
        float om = __shfl_xor(m, mask);
        int omi = __shfl_xor(mi, mask);
        if (om > m || (om == m && omi < mi)) { m = om; mi = omi; }
      }
      int pmi = __shfl_xor(mi, 1);
      if (q == 0) {
        v_lds[pb ^ 1][next] = m + fc[tt * 16 + next];
        if ((next & 1) == 0)
          bp4[t * 8 + (next >> 1)] = (unsigned char)((mi & 15) | ((pmi & 15) << 4));
      }
      __syncthreads();   // one barrier per step (double-buffered v)
    }
    if (c < 7) {
      #pragma unroll
      for (int i = 0; i < 16; ++i) ((float4*)fch[(c + 1) & 1])[i * 64 + l] = buf[i];
      __syncthreads();
    }
  }

  // after t = S-1 (odd), final v is in v_lds[0]
  float term = (l < 16) ? (v_lds[0][l] + trans[1 * 16 + l]) : -3.0e38f;
  int ti = (l < 16) ? l : 0;
  #pragma unroll
  for (int mask = 1; mask <= 32; mask <<= 1) {
    float om = __shfl_xor(term, mask);
    int omi = __shfl_xor(ti, mask);
    if (om > term || (om == term && omi < ti)) { term = om; ti = omi; }
  }
  if (l == 0) {
    out[0] = term;
    int tag = ti;
    out[1 + (S - 1)] = (float)tag;
    for (int t = S - 1; t >= 1; --t) {
      tag = (bp4[t * 8 + (tag >> 1)] >> ((tag & 1) * 4)) & 15;
      out[t] = (float)tag;   // out[1 + (t-1)]
    }
  }
}

extern "C" void kernel_launch(void* const* d_in, const int* in_sizes, int n_in,
                              void* d_out, int out_size, void* d_ws, size_t ws_size,
                              hipStream_t stream) {
  const int*   sent  = (const int*)d_in[0];
  const float* emb   = (const float*)d_in[1];
  const float* Wih_f = (const float*)d_in[2];
  const float* Whh_f = (const float*)d_in[3];
  const float* bih_f = (const float*)d_in[4];
  const float* bhh_f = (const float*)d_in[5];
  const float* Wih_b = (const float*)d_in[6];
  const float* Whh_b = (const float*)d_in[7];
  const float* bih_b = (const float*)d_in[8];
  const float* bhh_b = (const float*)d_in[9];
  const float* h0    = (const float*)d_in[10];
  const float* c0    = (const float*)d_in[11];
  const float* Wout  = (const float*)d_in[12];
  const float* bout  = (const float*)d_in[13];
  const float* trans = (const float*)d_in[14];
  float* out = (float*)d_out;

  // workspace layout
  char* ws = (char*)d_ws;
  float* xg     = (float*)(ws);                         // 2048*4096*4 = 32 MiB
  float* hs_cat = (float*)(ws + 33554432);              // 2048*1024*4 = 8 MiB
  float* feats  = (float*)(ws + 41943040);              // 2048*16*4 = 128 KiB
  ull*   hbuf   = (ull*)  (ws + 42074112);              // 8 reps * 16.5KB = 132 KiB
  int*   flags  = (int*)  (ws + 42209280);              // 32*64*4 = 8 KiB

  init_k<<<18, 512, 0, stream>>>(h0, hbuf, flags);
  fused_k<<<256, 256, 0, stream>>>(sent, emb, Wih_f, Wih_b, bih_f, bhh_f,
                                   bih_b, bhh_b, Whh_f, Whh_b, c0,
                                   xg, hbuf, hs_cat, flags);
  feats_k<<<2048, 64, 0, stream>>>(hs_cat, Wout, bout, feats);
  viterbi_k<<<1, 64, 0, stream>>>(feats, trans, out);
}

// Round 10
// 3918.677 us; speedup vs baseline: 1.1518x; 1.1518x over previous
//
#include <hip/hip_runtime.h>
#include <hip/hip_bf16.h>

#define S 2048
#define NEGV -10000.0f

typedef unsigned long long ull;
typedef unsigned int uint4v __attribute__((ext_vector_type(4)));

__device__ __forceinline__ float fsig(float x) {
  return 1.0f / (1.0f + __expf(-x));
}
__device__ __forceinline__ float ftanh(float x) {
  float a = fabsf(x);
  float e = __expf(-2.0f * a);
  float r = (1.0f - e) / (1.0f + e);
  return copysignf(r, x);
}

// ---------------- init: seed h0 (stamp 1) + clear flags, one launch ----------------
__global__ void init_k(const float* __restrict__ h0, ull* __restrict__ hbuf,
                       int* __restrict__ flags) {
  int b = blockIdx.x, u = threadIdx.x;
  if (b < 2) {                         // b = dir
    ull pk = (1ULL << 32) | (ull)__float_as_uint(h0[b * 512 + u]);
    __hip_atomic_store(&hbuf[b * 1024 + u], pk, __ATOMIC_RELAXED, __HIP_MEMORY_SCOPE_AGENT);
    __hip_atomic_store(&hbuf[b * 1024 + 512 + u], 0ULL, __ATOMIC_RELAXED, __HIP_MEMORY_SCOPE_AGENT);
  } else {
    flags[(b - 2) * 512 + u] = 0;      // blocks 2..5 clear 2048 ints
  }
}

// ---------------- FUSED: blocks 0..127 LSTM (R5/R8 chain), 128..255 persistent GEMM ----
// One block per CU. GEMM: chain-head-priority tiles, agent write-through publish + flag.
// LSTM: proven R8 chain: 16B sc0sc1 stamp-fused polls + sleep(1), publish-first,
// 2-step xg pipeline gated on tile flags at 64-row boundaries.
__global__ __launch_bounds__(256) void fused_k(
    const int* __restrict__ sent, const float* __restrict__ emb,
    const float* __restrict__ Wih_f, const float* __restrict__ Wih_b,
    const float* __restrict__ bih_f, const float* __restrict__ bhh_f,
    const float* __restrict__ bih_b, const float* __restrict__ bhh_b,
    const float* __restrict__ Whh_f, const float* __restrict__ Whh_b,
    const float* __restrict__ c0,
    float* __restrict__ xg,            // [S][4096]
    ull* __restrict__ hbuf,            // [2 dir][2 slot][512]
    float* __restrict__ hs_cat,        // [S][1024]
    int* __restrict__ flags)           // [32 by][64 bx]
{
  __shared__ __align__(16) float smem[4544];
  const int t = threadIdx.x;

  if (blockIdx.x >= 128) {
    // ================= persistent GEMM worker =================
    float* Asm = smem;                 // [64][36]
    float* Bsm = smem + 2304;          // [32][68]
    int*   sidx = (int*)(smem + 4480); // [64]
    const int tm = t >> 4, tn = t & 15;
    const int lr = t >> 2, lkq = t & 3;

    for (int i = 0; i < 16; ++i) {
      const int T = (blockIdx.x - 128) + 128 * i;   // priority rank
      const int byo = T >> 6, bxo = T & 63;
      const int by = (byo & 1) ? (31 - (byo >> 1)) : (byo >> 1);
      const int bx = (bxo & 1) ? (32 + (bxo >> 1)) : (bxo >> 1);
      const int n0 = bx * 64, m0 = by * 64;

      const float* W = (n0 < 2048) ? (Wih_f + (size_t)n0 * 1024)
                                   : (Wih_b + (size_t)(n0 - 2048) * 1024);
      __syncthreads();
      if (t < 64) sidx[t] = sent[m0 + t];
      __syncthreads();

      float acc[4][4] = {};
      for (int k0 = 0; k0 < 1024; k0 += 32) {
        const float* ap = emb + (size_t)sidx[lr] * 1024 + k0 + lkq * 8;
        float4 a0 = *(const float4*)ap;
        float4 a1 = *(const float4*)(ap + 4);
        const float* bp = W + (size_t)lr * 1024 + k0 + lkq * 8;
        float4 b0 = *(const float4*)bp;
        float4 b1 = *(const float4*)(bp + 4);
        __syncthreads();
        *(float4*)&Asm[lr * 36 + lkq * 8]     = a0;
        *(float4*)&Asm[lr * 36 + lkq * 8 + 4] = a1;
        {
          const float* bb0 = (const float*)&b0;
          const float* bb1 = (const float*)&b1;
          #pragma unroll
          for (int j = 0; j < 4; ++j) Bsm[(lkq * 8 + j) * 68 + lr] = bb0[j];
          #pragma unroll
          for (int j = 0; j < 4; ++j) Bsm[(lkq * 8 + 4 + j) * 68 + lr] = bb1[j];
        }
        __syncthreads();
        #pragma unroll
        for (int kk = 0; kk < 32; ++kk) {
          float a0_ = Asm[(tm * 4 + 0) * 36 + kk];
          float a1_ = Asm[(tm * 4 + 1) * 36 + kk];
          float a2_ = Asm[(tm * 4 + 2) * 36 + kk];
          float a3_ = Asm[(tm * 4 + 3) * 36 + kk];
          float4 bv = *(const float4*)&Bsm[kk * 68 + tn * 4];
          acc[0][0] = fmaf(a0_, bv.x, acc[0][0]); acc[0][1] = fmaf(a0_, bv.y, acc[0][1]);
          acc[0][2] = fmaf(a0_, bv.z, acc[0][2]); acc[0][3] = fmaf(a0_, bv.w, acc[0][3]);
          acc[1][0] = fmaf(a1_, bv.x, acc[1][0]); acc[1][1] = fmaf(a1_, bv.y, acc[1][1]);
          acc[1][2] = fmaf(a1_, bv.z, acc[1][2]); acc[1][3] = fmaf(a1_, bv.w, acc[1][3]);
          acc[2][0] = fmaf(a2_, bv.x, acc[2][0]); acc[2][1] = fmaf(a2_, bv.y, acc[2][1]);
          acc[2][2] = fmaf(a2_, bv.z, acc[2][2]); acc[2][3] = fmaf(a2_, bv.w, acc[2][3]);
          acc[3][0] = fmaf(a3_, bv.x, acc[3][0]); acc[3][1] = fmaf(a3_, bv.y, acc[3][1]);
          acc[3][2] = fmaf(a3_, bv.z, acc[3][2]); acc[3][3] = fmaf(a3_, bv.w, acc[3][3]);
        }
      }

      const float* bi = (n0 < 2048) ? bih_f : bih_b;
      const float* bh = (n0 < 2048) ? bhh_f : bhh_b;
      const int nb = (n0 < 2048) ? n0 : (n0 - 2048);
      #pragma unroll
      for (int ii = 0; ii < 4; ++ii) {
        int m = m0 + tm * 4 + ii;
        #pragma unroll
        for (int j = 0; j < 4; ++j) {
          int nn = tn * 4 + j;
          float bias = bi[nb + nn] + bh[nb + nn];
          __hip_atomic_store(&xg[(size_t)m * 4096 + n0 + nn], acc[ii][j] + bias,
                             __ATOMIC_RELAXED, __HIP_MEMORY_SCOPE_AGENT);
        }
      }
      asm volatile("s_waitcnt vmcnt(0)" ::: "memory");
      __syncthreads();
      if (t == 0)
        __hip_atomic_store(&flags[by * 64 + bx], 1, __ATOMIC_RELAXED, __HIP_MEMORY_SCOPE_AGENT);
    }
    return;
  }

  // ================= LSTM role (R8 chain) =================
  const int w = blockIdx.x;
  const int dir = w & 1;
  const int wid = w >> 1;              // 0..63
  const int rr = t >> 3;               // row-in-wg 0..31
  const int seg = t & 7;               // 0..7
  const int g  = rr & 3;               // gate 0..3 (i,f,g,o)
  const int ul = rr >> 2;              // local unit 0..7
  const int unit = wid * 8 + ul;       // 0..511
  const int grow = g * 512 + unit;     // global Whh row
  const int bxf  = dir * 32 + g * 8 + (wid >> 3);   // flag column for this row's xg

  float (*h_lds)[544] = (float(*)[544])smem;        // [2][544]

  const float* Whh = dir ? Whh_b : Whh_f;
  float wreg[64];
  {
    const float* src = Whh + (size_t)grow * 512 + seg * 64;
    #pragma unroll
    for (int j = 0; j < 16; ++j) {
      float4 v = *(const float4*)(src + j * 4);
      wreg[4 * j + 0] = v.x; wreg[4 * j + 1] = v.y;
      wreg[4 * j + 2] = v.z; wreg[4 * j + 3] = v.w;
    }
  }

  ull* hb = hbuf + dir * 1024;
  float c_reg = c0[dir * 512 + unit];  // meaningful on g==0 lanes

  const int u0 = t * 2;
  const int wchunk = u0 >> 6, wpos = u0 & 63;

  // initial xg: gate on the chain-head tile flags, then coherent loads
  float xg_a = 0.0f, xg_b = 0.0f;
  if (seg == 0) {
    int by0 = dir ? 31 : 0;
    while (__hip_atomic_load(&flags[by0 * 64 + bxf], __ATOMIC_RELAXED,
                             __HIP_MEMORY_SCOPE_AGENT) != 1)
      __builtin_amdgcn_s_sleep(8);
    int r0 = dir ? (S - 1) : 0;
    int r1 = dir ? (S - 2) : 1;
    xg_a = __hip_atomic_load(&xg[(size_t)r0 * 4096 + dir * 2048 + grow],
                             __ATOMIC_RELAXED, __HIP_MEMORY_SCOPE_AGENT);
    xg_b = __hip_atomic_load(&xg[(size_t)r1 * 4096 + dir * 2048 + grow],
                             __ATOMIC_RELAXED, __HIP_MEMORY_SCOPE_AGENT);
  }

  #define LSTM_STEP(K, XG_REG)                                                  \
  {                                                                             \
    const int k = (K);                                                          \
    float xgv = XG_REG;                                                         \
    if (seg == 0 && k + 2 < S) {       /* prefetch row k+2 into same reg */     \
      int rowk = dir ? (S - 3 - k) : (k + 2);                                   \
      if ((rowk & 63) == (dir ? 63 : 0)) {   /* entering new 64-row block */    \
        int byn = rowk >> 6;                                                    \
        while (__hip_atomic_load(&flags[byn * 64 + bxf], __ATOMIC_RELAXED,      \
                                 __HIP_MEMORY_SCOPE_AGENT) != 1)                \
          __builtin_amdgcn_s_sleep(8);                                          \
      }                                                                         \
      XG_REG = __hip_atomic_load(&xg[(size_t)rowk * 4096 + dir * 2048 + grow],  \
                                 __ATOMIC_RELAXED, __HIP_MEMORY_SCOPE_AGENT);   \
    }                                                                           \
    /* poll h_k: stamp k+1 in slot k&1; 16B coherent load, sleep backoff */     \
    {                                                                           \
      ull* src = hb + (k & 1) * 512 + u0;                                       \
      const unsigned want = (unsigned)(k + 1);                                  \
      uint4v v;                                                                 \
      asm volatile("global_load_dwordx4 %0, %1, off sc0 sc1"                    \
                   : "=v"(v) : "v"(src) : "memory");                            \
      asm volatile("s_waitcnt vmcnt(0)" ::: "memory");                          \
      while (v.y != want || v.w != want) {                                      \
        __builtin_amdgcn_s_sleep(1);                                            \
        asm volatile("global_load_dwordx4 %0, %1, off sc0 sc1"                  \
                     : "=v"(v) : "v"(src) : "memory");                          \
        asm volatile("s_waitcnt vmcnt(0)" ::: "memory");                        \
      }                                                                         \
      float* dst = &h_lds[k & 1][wchunk * 68 + wpos];                           \
      dst[0] = __uint_as_float(v.x);                                            \
      dst[1] = __uint_as_float(v.z);                                            \
    }                                                                           \
    __syncthreads();                                                            \
    /* 64-wide partial dot of row `grow` */                                     \
    const float* hl = &h_lds[k & 1][0];                                         \
    float p0 = 0.f, p1 = 0.f, p2 = 0.f, p3 = 0.f;                               \
    const float4* h4 = (const float4*)(hl + seg * 68);                          \
    _Pragma("unroll")                                                           \
    for (int j = 0; j < 16; ++j) {                                              \
      float4 hv = h4[j];                                                        \
      p0 = fmaf(wreg[4 * j + 0], hv.x, p0);                                     \
      p1 = fmaf(wreg[4 * j + 1], hv.y, p1);                                     \
      p2 = fmaf(wreg[4 * j + 2], hv.z, p2);                                     \
      p3 = fmaf(wreg[4 * j + 3], hv.w, p3);                                     \
    }                                                                           \
    float p = (p0 + p1) + (p2 + p3) + xgv;                                      \
    p += __shfl_xor(p, 1);                                                      \
    p += __shfl_xor(p, 2);                                                      \
    p += __shfl_xor(p, 4);                                                      \
    float gb_ = __shfl_xor(p, 8);      /* gate g^1 */                           \
    float gc_ = __shfl_xor(p, 16);     /* gate g^2 */                           \
    float gd_ = __shfl_xor(gb_, 16);   /* gate g^3 */                           \
    if (g == 0) {                                                               \
      float iv = fsig(p), fv = fsig(gb_), ov = fsig(gd_);                       \
      float gv = ftanh(gc_);                                                    \
      c_reg = fv * c_reg + iv * gv;                                             \
      float hv = ov * ftanh(c_reg);                                             \
      if (seg == 0) {                                                           \
        ull pk = ((ull)(unsigned)(k + 2) << 32) | (ull)__float_as_uint(hv);     \
        __hip_atomic_store(&hb[((k + 1) & 1) * 512 + unit], pk,                 \
                           __ATOMIC_RELAXED, __HIP_MEMORY_SCOPE_AGENT);         \
        int orig = dir ? (S - 1 - k) : k;                                       \
        hs_cat[(size_t)orig * 1024 + dir * 512 + unit] = hv;                    \
      }                                                                         \
    }                                                                           \
  }

  for (int kk = 0; kk < S; kk += 2) {
    LSTM_STEP(kk, xg_a);
    LSTM_STEP(kk + 1, xg_b);
  }
  #undef LSTM_STEP
}

// ---------------- feats[t][j] = hs_cat[t] . Wout[j] + bout[j] ----------------
__global__ __launch_bounds__(64) void feats_k(
    const float* __restrict__ hs_cat, const float* __restrict__ Wout,
    const float* __restrict__ bout, float* __restrict__ feats)
{
  int tpos = blockIdx.x;
  int l = threadIdx.x;
  int j = l & 15, q = l >> 4;
  const float* h = hs_cat + (size_t)tpos * 1024 + q * 256;
  const float* wv = Wout + (size_t)j * 1024 + q * 256;
  float s = 0.f;
  #pragma unroll 8
  for (int i = 0; i < 256; i += 4) {
    float4 hv = *(const float4*)(h + i);
    float4 ww = *(const float4*)(wv + i);
    s = fmaf(hv.x, ww.x, s); s = fmaf(hv.y, ww.y, s);
    s = fmaf(hv.z, ww.z, s); s = fmaf(hv.w, ww.w, s);
  }
  s += __shfl_xor(s, 16);
  s += __shfl_xor(s, 32);
  if (q == 0) feats[tpos * 16 + j] = s + bout[j];
}

// ---------------- Viterbi: single wave, register-resident v, zero barriers ----------
// v replicated: lane l holds v[l&15]. Per step: 4 width-16 shfl prev-gathers,
// in-lane argmax over 4 prevs (first-index ties), 2 shfl_xor cross-q reduce,
// v += feat (8-deep register prefetch). Backpointer map (16 x 4bit = one ull)
// packed via 4 ballots + bit-spread, stored to LDS. Backtrack = parallel suffix
// scan of map compositions (lane-local 32 + 6-round shfl scan), then each lane
// emits its 32 tags.
__device__ __forceinline__ ull compose_map(ull a, ull b) {
  // r[i] = a[b[i]]
  ull r = 0;
  #pragma unroll
  for (int i = 0; i < 16; ++i) {
    int bi = (int)((b >> (4 * i)) & 15);
    int ai = (int)((a >> (4 * bi)) & 15);
    r |= (ull)ai << (4 * i);
  }
  return r;
}

__device__ __forceinline__ ull spread16(ull x) {
  x &= 0xFFFFULL;
  x = (x | (x << 24)) & 0x000000FF000000FFULL;
  x = (x | (x << 12)) & 0x000F000F000F000FULL;
  x = (x | (x << 6))  & 0x0303030303030303ULL;
  x = (x | (x << 3))  & 0x1111111111111111ULL;
  return x;
}

__global__ __launch_bounds__(64, 1) void viterbi_k(
    const float* __restrict__ feats, const float* __restrict__ trans,
    float* __restrict__ out)
{
  __shared__ ull bpm[S];               // 16 KB: per-step tag maps
  const int l = threadIdx.x;
  const int next = l & 15, q4 = (l >> 4) * 4;

  const float tr0 = trans[next * 16 + q4 + 0];
  const float tr1 = trans[next * 16 + q4 + 1];
  const float tr2 = trans[next * 16 + q4 + 2];
  const float tr3 = trans[next * 16 + q4 + 3];

  float vcur = (next == 0) ? 0.0f : NEGV;   // START = 0

  #define VSTEP(T, FREG)                                                        \
  {                                                                             \
    float pv0 = __shfl(vcur, q4 + 0, 16);                                       \
    float pv1 = __shfl(vcur, q4 + 1, 16);                                       \
    float pv2 = __shfl(vcur, q4 + 2, 16);                                       \
    float pv3 = __shfl(vcur, q4 + 3, 16);                                       \
    float m = pv0 + tr0; int mi = q4;                                           \
    float s1 = pv1 + tr1; if (s1 > m) { m = s1; mi = q4 + 1; }                  \
    float s2 = pv2 + tr2; if (s2 > m) { m = s2; mi = q4 + 2; }                  \
    float s3 = pv3 + tr3; if (s3 > m) { m = s3; mi = q4 + 3; }                  \
    { float om = __shfl_xor(m, 16); int omi = __shfl_xor(mi, 16);               \
      if (om > m || (om == m && omi < mi)) { m = om; mi = omi; } }              \
    { float om = __shfl_xor(m, 32); int omi = __shfl_xor(mi, 32);               \
      if (om > m || (om == m && omi < mi)) { m = om; mi = omi; } }              \
    vcur = m + (FREG);                                                          \
    ull b0 = __ballot(mi & 1) & 0xFFFFULL;                                      \
    ull b1 = __ballot(mi & 2) & 0xFFFFULL;                                      \
    ull b2 = __ballot(mi & 4) & 0xFFFFULL;                                      \
    ull b3 = __ballot(mi & 8) & 0xFFFFULL;                                      \
    ull map = spread16(b0) | (spread16(b1) << 1) |                              \
              (spread16(b2) << 2) | (spread16(b3) << 3);                        \
    if (l == 0) bpm[T] = map;                                                   \
  }

  // 8-deep rolling feats prefetch (1 cache line per step, L2/L3-resident)
  float f0 = feats[0 * 16 + next], f1 = feats[1 * 16 + next];
  float f2 = feats[2 * 16 + next], f3 = feats[3 * 16 + next];
  float f4 = feats[4 * 16 + next], f5 = feats[5 * 16 + next];
  float f6 = feats[6 * 16 + next], f7 = feats[7 * 16 + next];

  for (int t = 0; t < S; t += 8) {
    VSTEP(t + 0, f0); if (t + 8  < S) f0 = feats[(t + 8)  * 16 + next];
    VSTEP(t + 1, f1); if (t + 9  < S) f1 = feats[(t + 9)  * 16 + next];
    VSTEP(t + 2, f2); if (t + 10 < S) f2 = feats[(t + 10) * 16 + next];
    VSTEP(t + 3, f3); if (t + 11 < S) f3 = feats[(t + 11) * 16 + next];
    VSTEP(t + 4, f4); if (t + 12 < S) f4 = feats[(t + 12) * 16 + next];
    VSTEP(t + 5, f5); if (t + 13 < S) f5 = feats[(t + 13) * 16 + next];
    VSTEP(t + 6, f6); if (t + 14 < S) f6 = feats[(t + 14) * 16 + next];
    VSTEP(t + 7, f7); if (t + 15 < S) f7 = feats[(t + 15) * 16 + next];
  }
  #undef VSTEP

  // terminal = v + trans[STOP=1][:]; argmax with first-index ties
  float term = vcur + trans[16 + next];
  int ti = next;
  #pragma unroll
  for (int mask = 1; mask <= 8; mask <<= 1) {
    float om = __shfl_xor(term, mask);
    int omi = __shfl_xor(ti, mask);
    if (om > term || (om == term && omi < ti)) { term = om; ti = omi; }
  }
  // all lanes now hold (term, ti=best) — groups are replicas

  __syncthreads();   // bpm (lane-0 writes) visible to all lanes

  // lane-local product L = bp_{32l} ∘ ... ∘ bp_{32l+31}  (latest applied first)
  ull M = bpm[32 * l + 31];
  for (int i = 30; i >= 0; --i) M = compose_map(bpm[32 * l + i], M);

  // inclusive suffix scan across lanes: Sm_l = L_l ∘ L_{l+1} ∘ ... ∘ L_63
  ull Sm = M;
  #pragma unroll
  for (int d = 1; d < 64; d <<= 1) {
    ull o = __shfl_down(Sm, d);
    if (l + d < 64) Sm = compose_map(Sm, o);
  }
  ull G = __shfl_down(Sm, 1);          // G_l = suffix over later lanes
  if (l == 63) G = 0xFEDCBA9876543210ULL;   // identity

  int cur = (int)((G >> (4 * ti)) & 15);    // tag @ t = 32l+31
  for (int i = 31; i >= 1; --i) {
    int t = 32 * l + i;
    out[1 + t] = (float)cur;
    cur = (int)((bpm[t] >> (4 * cur)) & 15);   // tag @ t-1
  }
  out[1 + 32 * l] = (float)cur;
  if (l == 0) out[0] = term;
}

extern "C" void kernel_launch(void* const* d_in, const int* in_sizes, int n_in,
                              void* d_out, int out_size, void* d_ws, size_t ws_size,
                              hipStream_t stream) {
  const int*   sent  = (const int*)d_in[0];
  const float* emb   = (const float*)d_in[1];
  const float* Wih_f = (const float*)d_in[2];
  const float* Whh_f = (const float*)d_in[3];
  const float* bih_f = (const float*)d_in[4];
  const float* bhh_f = (const float*)d_in[5];
  const float* Wih_b = (const float*)d_in[6];
  const float* Whh_b = (const float*)d_in[7];
  const float* bih_b = (const float*)d_in[8];
  const float* bhh_b = (const float*)d_in[9];
  const float* h0    = (const float*)d_in[10];
  const float* c0    = (const float*)d_in[11];
  const float* Wout  = (const float*)d_in[12];
  const float* bout  = (const float*)d_in[13];
  const float* trans = (const float*)d_in[14];
  float* out = (float*)d_out;

  // workspace layout
  char* ws = (char*)d_ws;
  float* xg     = (float*)(ws);                         // 2048*4096*4 = 32 MiB
  float* hs_cat = (float*)(ws + 33554432);              // 2048*1024*4 = 8 MiB
  float* feats  = (float*)(ws + 41943040);              // 2048*16*4 = 128 KiB
  ull*   hbuf   = (ull*)  (ws + 42074112);              // 2*2*512*8 = 16 KiB
  int*   flags  = (int*)  (ws + 42090496);              // 32*64*4 = 8 KiB

  init_k<<<6, 512, 0, stream>>>(h0, hbuf, flags);
  fused_k<<<256, 256, 0, stream>>>(sent, emb, Wih_f, Wih_b, bih_f, bhh_f,
                                   bih_b, bhh_b, Whh_f, Whh_b, c0,
                                   xg, hbuf, hs_cat, flags);
  feats_k<<<2048, 64, 0, stream>>>(hs_cat, Wout, bout, feats);
  viterbi_k<<<1, 64, 0, stream>>>(feats, trans, out);
}